// Round 3
// baseline (786.923 us; speedup 1.0000x reference)
//
#include <hip/hip_runtime.h>
#include <hip/hip_bf16.h>

#define Dn 200
#define Cn 8
#define Gn 10000
#define Vn 20000
#define VGn 50000
#define GLn 500
#define EPSf 1e-8f

// Stirling series, valid (accurate) for y >= 8
__device__ __forceinline__ float stirling_lg(float y) {
    float ly  = __logf(y);
    float iv  = __builtin_amdgcn_rcpf(y);
    float iv2 = iv * iv;
    float ser = iv * (0.08333333333333f + iv2 * (-0.00277777777778f + iv2 * 0.00079365079365f));
    return fmaf(y - 0.5f, ly, -y) + 0.91893853320467274f + ser;
}

// generic lgamma for x > 0 (used only in preambles, amortized)
__device__ float lgamma_gen(float x) {
    float p = 1.0f;
    float y = x;
    while (y < 8.0f) { p *= y; y += 1.0f; }
    return stirling_lg(y) - __logf(p);
}

__global__ __launch_bounds__(256, 2) void elbo_kernel(
    const float* __restrict__ fc_log,
    const float* __restrict__ genotypes,
    const float* __restrict__ obs,
    const float* __restrict__ lib,
    const float* __restrict__ baseline_log,
    const float* __restrict__ dispersion_log,
    const int* __restrict__ v2g,
    const int* __restrict__ lv_sel,
    const int* __restrict__ v2lg,
    float* __restrict__ out)
{
    __shared__ float s_loglib[Dn];     // log(lib[d,c]) for this block's c
    __shared__ float s_ltab[128];      // lgamma(1+n)
    __shared__ float s_small[8 * 256]; // per-thread lgamma(r+v), v=0..7

    const int tid = threadIdx.x;
    const int c   = blockIdx.y;
    int vg = blockIdx.x * 256 + tid;
    const bool active = (vg < VGn);
    if (!active) vg = VGn - 1;

    // ---- block preamble ----
    if (tid < 128) s_ltab[tid] = lgamma_gen(1.0f + (float)tid);
    if (tid < Dn)  s_loglib[tid] = __logf(lib[tid * Cn + c]);

    // ---- per-thread (c,vg) params, amortized over 100 d-iterations ----
    const int lv   = lv_sel[vg];
    const int lg   = v2lg[vg];
    const int gene = v2g[vg];

    const float fc   = fc_log[c * VGn + vg];
    const float blog = baseline_log[c * Gn + gene];
    const float dlog = dispersion_log[c * Gn + gene];

    const float disp = fminf(__expf(dlog), 20.0f);
    const float r    = 1.0f / disp;           // hoisted, full-precision divide
    const float glr  = lgamma_gen(r);
    const float K    = glr - r * __logf(r + EPSf);
    const float r2e  = r + 2.0f * EPSf;

    {   // per-thread small table: lgamma(r+v) = lgamma(r) + log(prod_{k<v}(r+k))
        float p = 1.0f;
        #pragma unroll
        for (int v = 0; v < 8; ++v) {
            s_small[v * 256 + tid] = glr + __logf(p);
            p *= (r + (float)v);
        }
    }
    __syncthreads();

    // ---- main loop over donors (split in 2 via blockIdx.z) ----
    const int d0 = blockIdx.z * (Dn / 2);
    const float* gp = genotypes + (size_t)d0 * Vn + lv;
    const float* op = obs + ((size_t)d0 * Cn + c) * GLn + lg;
    float* wp = out + ((size_t)d0 * Cn + c) * VGn + vg;

    #pragma unroll 4
    for (int i = 0; i < Dn / 2; ++i) {
        const float g     = *gp; gp += Vn;
        const float value = *op; op += Cn * GLn;

        const float s  = fmaf(g, fc, blog + s_loglib[d0 + i]);
        const float mu = __expf(s);
        const float L  = __logf(r2e + mu);
        const float rv = r + value;

        int vi = (int)value;
        vi = vi < 0 ? 0 : (vi > 127 ? 127 : vi);
        const int vis = vi < 7 ? vi : 7;

        const float lg_big   = stirling_lg(rv);            // valid when value>=8
        const float lg_small = s_small[vis * 256 + tid];   // valid when value<8
        const float lgrv     = (vi < 8) ? lg_small : lg_big;

        const float e = fmaf(rv, L, K) - value * s + s_ltab[vi] - lgrv;

        if (active) *wp = e;
        wp += Cn * VGn;
    }
}

extern "C" void kernel_launch(void* const* d_in, const int* in_sizes, int n_in,
                              void* d_out, int out_size, void* d_ws, size_t ws_size,
                              hipStream_t stream) {
    const float* fc_log         = (const float*)d_in[0];
    const float* genotypes      = (const float*)d_in[1];
    const float* obs            = (const float*)d_in[2];
    const float* lib            = (const float*)d_in[3];
    const float* baseline_log   = (const float*)d_in[4];
    const float* dispersion_log = (const float*)d_in[5];
    const int* v2g    = (const int*)d_in[6];
    const int* lv_sel = (const int*)d_in[7];
    const int* v2lg   = (const int*)d_in[8];
    float* out = (float*)d_out;

    dim3 grid((VGn + 255) / 256, Cn, 2);
    elbo_kernel<<<grid, 256, 0, stream>>>(fc_log, genotypes, obs, lib,
                                          baseline_log, dispersion_log,
                                          v2g, lv_sel, v2lg, out);
}